// Round 12
// baseline (512.175 us; speedup 1.0000x reference)
//
#include <hip/hip_runtime.h>
#include <hip/hip_fp16.h>
#include <hip/hip_fp8.h>

// EquivSetGNN forward, MI355X.
// R12: R11's fp8-gather was neutral -> gathers are latency/fixed-cost bound, not
// byte-bound. This round cuts fixed costs: (1) zgather fused into catmm_w3 —
// each wave gathers its own 16-node z tile into wave-private LDS then MFMAs from
// it (kills 2 dispatches + 51MB z round-trip); (2) rowoff_diff + prep_w merged.
// 13 -> 10 dispatches. Tables stay fp8 (h: 6.4MB, Xe: 3.2MB L2-resident).

constexpr int NN = 100000;   // nodes
constexpr int NE = 50000;    // hyperedges
constexpr int NZ = 1280000;  // incidences
constexpr int NG = 256;      // graphs
constexpr int NTILE = NN / 16;  // 6250 row-tiles of 16
constexpr int CB = 196;         // coarse buckets = ceil(NE/256)
constexpr int CAP = 8192;       // bucket region capacity (words)
constexpr int CHUNK = 4000;
constexpr int NBLK_A = NZ / CHUNK;   // 320
constexpr int NBLK_ROW = (NZ + 255) / 256;  // 5000

constexpr float SH = 64.0f;   // h scale
constexpr float SX = 512.0f;  // Xe scale

typedef _Float16 h8 __attribute__((ext_vector_type(8)));
typedef float f4 __attribute__((ext_vector_type(4)));
typedef unsigned char u8;

constexpr int OFF_IN  = 0;
constexpr int OFF_1A  = 8192;
constexpr int OFF_1B  = 12288;
constexpr int OFF_W2  = 16384;
constexpr int OFF_W3  = 24576;
constexpr int OFF_C1  = 28672;
constexpr int OFF_C2  = 32768;
constexpr int WBUF_HALVES = 34816;

__device__ __forceinline__ u8 enc8(float v) {
  __hip_fp8_e4m3 t(v);
  return *reinterpret_cast<u8*>(&t);
}
__device__ __forceinline__ float dec8(u8 b) {
  __hip_fp8_e4m3 t;
  *reinterpret_cast<u8*>(&t) = b;
  return (float)t;
}

__device__ __forceinline__ int lbound(const int* a, int n, int v) {
  int lo = 0, hi = n;
  while (lo < hi) { int m = (lo + hi) >> 1; if (a[m] < v) lo = m + 1; else hi = m; }
  return lo;
}

__device__ __forceinline__ f4 zero4() { f4 z; z[0]=0.f; z[1]=0.f; z[2]=0.f; z[3]=0.f; return z; }

__device__ __forceinline__ h8 ld_a32(const float* p) {
  const f4* v = (const f4*)p;
  f4 lo = v[0], hi = v[1];
  h8 r;
  r[0]=(_Float16)lo[0]; r[1]=(_Float16)lo[1]; r[2]=(_Float16)lo[2]; r[3]=(_Float16)lo[3];
  r[4]=(_Float16)hi[0]; r[5]=(_Float16)hi[1]; r[6]=(_Float16)hi[2]; r[7]=(_Float16)hi[3];
  return r;
}

#define MFMA(a, b, c) __builtin_amdgcn_mfma_f32_16x16x32_f16((a), (b), (c), 0, 0, 0)

// ---- Pass A: coarse bin into fixed-capacity regions, packed ((dst&255)<<24 | src) ----
__global__ void __launch_bounds__(256) binA_k(const int* __restrict__ src,
    const int* __restrict__ dst, int* __restrict__ bcnt, unsigned int* __restrict__ words) {
  __shared__ int cnt[CB];
  __shared__ int base[CB];
  int t = threadIdx.x;
  int start = blockIdx.x * CHUNK;
  for (int i = t; i < CB; i += 256) cnt[i] = 0;
  __syncthreads();
  for (int i = start + t; i < start + CHUNK; i += 256)
    atomicAdd(&cnt[dst[i] >> 8], 1);
  __syncthreads();
  for (int i = t; i < CB; i += 256) base[i] = atomicAdd(&bcnt[i], cnt[i]);
  __syncthreads();
  for (int i = t; i < CB; i += 256) cnt[i] = 0;  // reuse as cursor
  __syncthreads();
  for (int i = start + t; i < start + CHUNK; i += 256) {
    int d = dst[i];
    int b = d >> 8;
    int p = base[b] + atomicAdd(&cnt[b], 1);
    words[(size_t)b * CAP + p] = (unsigned)src[i] | ((unsigned)(d & 255) << 24);
  }
}

// ---- Pass B: per bucket — bucket-base scan, histogram, 256-scan, off/invE,
//      exact scatter via LDS, coalesced copy-out ----
__global__ void __launch_bounds__(256) binB_k(const unsigned int* __restrict__ words,
    const int* __restrict__ bcnt,
    int* __restrict__ off, float* __restrict__ invE, int* __restrict__ csr,
    int ne, int nnz) {
  __shared__ int buf[CAP];
  __shared__ int hist[256];
  __shared__ int sh[256];
  __shared__ int cur[256];
  __shared__ int shb[256];
  int b = blockIdx.x, t = threadIdx.x;
  int e0 = b << 8;
  int ecnt = min(256, ne - e0);
  int cntb = bcnt[b];
  shb[t] = (t < CB) ? bcnt[t] : 0;
  __syncthreads();
  for (int ofs = 1; ofs < 256; ofs <<= 1) {
    int v = (t >= ofs) ? shb[t - ofs] : 0;
    __syncthreads();
    shb[t] += v;
    __syncthreads();
  }
  int gbase = shb[b] - cntb;
  const unsigned int* wp = words + (size_t)b * CAP;
  hist[t] = 0;
  __syncthreads();
  for (int i = t; i < cntb; i += 256) atomicAdd(&hist[wp[i] >> 24], 1);
  __syncthreads();
  int c = hist[t];
  sh[t] = c;
  __syncthreads();
  for (int ofs = 1; ofs < 256; ofs <<= 1) {
    int v = (t >= ofs) ? sh[t - ofs] : 0;
    __syncthreads();
    sh[t] += v;
    __syncthreads();
  }
  int excl = sh[t] - c;
  if (t < ecnt) {
    off[e0 + t] = gbase + excl;
    invE[e0 + t] = 1.0f / (float)max(c, 1);
  }
  if (b == CB - 1 && t == 0) off[ne] = nnz;
  cur[t] = excl;
  __syncthreads();
  for (int i = t; i < cntb; i += 256) {
    unsigned w = wp[i];
    int s = (int)(w & 0xFFFFFFu);
    int p = atomicAdd(&cur[w >> 24], 1);
    if (p < CAP) buf[p] = s;
    else csr[gbase + p] = s;  // statistically never
  }
  __syncthreads();
  int lim = min(cntb, CAP);
  for (int i = t; i < lim; i += 256) csr[gbase + i] = buf[i];
}

// ---- merged: roff from sorted src (+bcnt zero) | weight-fragment prep ----
__global__ void __launch_bounds__(256) prep_misc_k(const int* __restrict__ src,
    int* __restrict__ roff, int* __restrict__ bcnt, int n, int nnz,
    const float* __restrict__ W_in, const float* __restrict__ W1a,
    const float* __restrict__ W1b, const float* __restrict__ W2,
    const float* __restrict__ W3,  const float* __restrict__ Wc1,
    const float* __restrict__ Wc2, _Float16* __restrict__ wbuf) {
  int blk = blockIdx.x;
  if (blk < NBLK_ROW) {
    if (blk == 0 && threadIdx.x < 256) bcnt[threadIdx.x] = 0;
    int i = blk * 256 + threadIdx.x;
    if (i >= nnz) return;
    int s = src[i];
    int prev = (i == 0) ? -1 : src[i - 1];
    for (int v = prev + 1; v <= s; ++v) roff[v] = i;
    if (i == nnz - 1) {
      for (int v = s + 1; v <= n; ++v) roff[v] = nnz;
    }
    return;
  }
  int b = blk - NBLK_ROW;
  int l = threadIdx.x;
  if (l >= 64) return;
  const float* srcw; int K, J; _Float16* dstw; int tile;
  if      (b < 16) { srcw = W_in; K = 128; J = 64; dstw = wbuf + OFF_IN; tile = b; }
  else if (b < 24) { srcw = W1a;  K = 64;  J = 64; dstw = wbuf + OFF_1A; tile = b - 16; }
  else if (b < 32) { srcw = W1b;  K = 64;  J = 64; dstw = wbuf + OFF_1B; tile = b - 24; }
  else if (b < 48) { srcw = W2;   K = 128; J = 64; dstw = wbuf + OFF_W2; tile = b - 32; }
  else if (b < 56) { srcw = W3;   K = 64;  J = 64; dstw = wbuf + OFF_W3; tile = b - 48; }
  else if (b < 64) { srcw = Wc1;  K = 64;  J = 64; dstw = wbuf + OFF_C1; tile = b - 56; }
  else             { srcw = Wc2;  K = 64;  J = 32; dstw = wbuf + OFF_C2; tile = b - 64; }
  int KS = K / 32;
  int jt = tile / KS, ks = tile % KS;
  int q = l >> 4, m = l & 15;
#pragma unroll
  for (int j = 0; j < 8; ++j)
    dstw[((size_t)tile * 64 + l) * 8 + j] =
        (_Float16)srcw[(size_t)(ks * 32 + q * 8 + j) * J + jt * 16 + m];
}

// ---- x = relu(X @ W_in + b); x0 = x. fp16 outputs (unchanged) ----
__global__ void __launch_bounds__(256) mm_in_mfma(const float* __restrict__ A,
    const _Float16* __restrict__ wbuf, const float* __restrict__ b,
    __half* __restrict__ C, __half* __restrict__ C2, int ntiles) {
  int l = threadIdx.x & 63, q = l >> 4, m16 = l & 15;
  int wid = (blockIdx.x * blockDim.x + threadIdx.x) >> 6;
  int nw = (gridDim.x * blockDim.x) >> 6;
  const h8* wf = (const h8*)(wbuf + OFF_IN);
  h8 w[16];
#pragma unroll
  for (int f = 0; f < 16; ++f) w[f] = wf[f * 64 + l];
  float bv[4];
#pragma unroll
  for (int jt = 0; jt < 4; ++jt) bv[jt] = b[jt * 16 + m16];
  for (int t = wid; t < ntiles; t += nw) {
    int rbase = t * 16;
    const float* rp = A + (size_t)(rbase + m16) * 128 + q * 8;
    h8 a0 = ld_a32(rp), a1 = ld_a32(rp + 32), a2 = ld_a32(rp + 64), a3 = ld_a32(rp + 96);
    f4 acc[4];
#pragma unroll
    for (int jt = 0; jt < 4; ++jt) {
      acc[jt] = zero4();
      acc[jt] = MFMA(a0, w[jt * 4 + 0], acc[jt]);
      acc[jt] = MFMA(a1, w[jt * 4 + 1], acc[jt]);
      acc[jt] = MFMA(a2, w[jt * 4 + 2], acc[jt]);
      acc[jt] = MFMA(a3, w[jt * 4 + 3], acc[jt]);
    }
#pragma unroll
    for (int jt = 0; jt < 4; ++jt)
#pragma unroll
      for (int r = 0; r < 4; ++r) {
        __half v = __float2half(fmaxf(acc[jt][r] + bv[jt], 0.0f));
        size_t idx = (size_t)(rbase + q * 4 + r) * 64 + jt * 16 + m16;
        C[idx] = v; C2[idx] = v;
      }
  }
}

// ---- h = relu(x@W1a+b1a)@W1b + b1b; fp16 in, fp8(xSH) out via LDS transpose ----
__global__ void __launch_bounds__(256) mm_dual_mfma(const __half* __restrict__ x,
    const _Float16* __restrict__ wbuf, const float* __restrict__ b1a,
    const float* __restrict__ b1b, u8* __restrict__ hf8, int ntiles) {
  __shared__ float lds[4][16 * 68];
  int l = threadIdx.x & 63, q = l >> 4, m16 = l & 15, wv = threadIdx.x >> 6;
  int wid = (blockIdx.x * blockDim.x + threadIdx.x) >> 6;
  int nw = (gridDim.x * blockDim.x) >> 6;
  const h8* wap = (const h8*)(wbuf + OFF_1A);
  const h8* wbp = (const h8*)(wbuf + OFF_1B);
  h8 wa[8], wb[8];
#pragma unroll
  for (int f = 0; f < 8; ++f) { wa[f] = wap[f * 64 + l]; wb[f] = wbp[f * 64 + l]; }
  float bav[4], bbv[4];
#pragma unroll
  for (int jt = 0; jt < 4; ++jt) { bav[jt] = b1a[jt * 16 + m16]; bbv[jt] = b1b[jt * 16 + m16]; }
  float* myl = lds[wv];
  for (int t = wid; t < ntiles; t += nw) {
    int rbase = t * 16;
    const __half* rp = x + (size_t)(rbase + m16) * 64 + q * 8;
    h8 a0 = *(const h8*)rp, a1 = *(const h8*)(rp + 32);
    f4 acc[4];
#pragma unroll
    for (int jt = 0; jt < 4; ++jt) {
      acc[jt] = zero4();
      acc[jt] = MFMA(a0, wa[jt * 2 + 0], acc[jt]);
      acc[jt] = MFMA(a1, wa[jt * 2 + 1], acc[jt]);
    }
#pragma unroll
    for (int jt = 0; jt < 4; ++jt)
#pragma unroll
      for (int r = 0; r < 4; ++r)
        myl[(q * 4 + r) * 68 + jt * 16 + m16] = fmaxf(acc[jt][r] + bav[jt], 0.0f);
    h8 t0, t1;
#pragma unroll
    for (int j = 0; j < 8; ++j) t0[j] = (_Float16)myl[m16 * 68 + q * 8 + j];
#pragma unroll
    for (int j = 0; j < 8; ++j) t1[j] = (_Float16)myl[m16 * 68 + 32 + q * 8 + j];
#pragma unroll
    for (int jt = 0; jt < 4; ++jt) {
      acc[jt] = zero4();
      acc[jt] = MFMA(t0, wb[jt * 2 + 0], acc[jt]);
      acc[jt] = MFMA(t1, wb[jt * 2 + 1], acc[jt]);
    }
#pragma unroll
    for (int jt = 0; jt < 4; ++jt)
#pragma unroll
      for (int r = 0; r < 4; ++r)
        myl[(q * 4 + r) * 68 + jt * 16 + m16] = acc[jt][r] + bbv[jt];
    union { uint4 u; u8 b[16]; } pk;
#pragma unroll
    for (int j = 0; j < 16; ++j) pk.b[j] = enc8(SH * myl[m16 * 68 + q * 16 + j]);
    *(uint4*)(hf8 + (size_t)(rbase + m16) * 64 + q * 16) = pk.u;
  }
}

// ---- V->E pull: fp8 h in (xSH), fp8 Xe out (xSX) (unchanged) ----
__global__ void __launch_bounds__(256) ve_pull_k(const u8* __restrict__ hf8,
    const int* __restrict__ csr, const int* __restrict__ off,
    const float* __restrict__ invE, u8* __restrict__ Xe, int e) {
  int lane = threadIdx.x & 63;
  int w = (blockIdx.x * blockDim.x + threadIdx.x) >> 6;
  if (w >= e) return;
  int lo = off[w], end = off[w + 1];
  int g = lane >> 3, c = lane & 7;
  float acc[8];
#pragma unroll
  for (int j = 0; j < 8; ++j) acc[j] = 0.0f;
  for (int i = lo + g; i < end; i += 8) {
    int r = csr[i];
    union { uint2 u; u8 b[8]; } pk;
    pk.u = *(const uint2*)(hf8 + (size_t)r * 64 + c * 8);
#pragma unroll
    for (int j = 0; j < 8; ++j) acc[j] += dec8(pk.b[j]);
  }
#pragma unroll
  for (int j = 0; j < 8; ++j) {
    acc[j] += __shfl_xor(acc[j], 8);
    acc[j] += __shfl_xor(acc[j], 16);
    acc[j] += __shfl_xor(acc[j], 32);
  }
  if (g == 0) {
    float s = invE[w] * (SX / SH);
    union { uint2 u; u8 b[8]; } pk;
#pragma unroll
    for (int j = 0; j < 8; ++j) pk.b[j] = enc8(acc[j] * s);
    *(uint2*)(Xe + (size_t)w * 64 + c * 8) = pk.u;
  }
}

// ---- fused: z-gather (per-wave, 16 nodes) + res = 0.5*x0 + mask*0.5*(cat(x,z)@W2+b2);
//      x = relu(res@W3+b3). ----
__global__ void __launch_bounds__(256) catmm_w3_mfma(__half* __restrict__ x,
    const u8* __restrict__ Xe, const __half* __restrict__ x0,
    const int* __restrict__ roff, const int* __restrict__ dstArr,
    const _Float16* __restrict__ wbuf,
    const float* __restrict__ b2, const float* __restrict__ b3, int ntiles) {
  __shared__ float lds[4][16 * 68];   // transpose buffer (per wave)
  __shared__ float zls[4][16 * 68];   // z tile (per wave)
  int l = threadIdx.x & 63, q = l >> 4, m16 = l & 15, wv = threadIdx.x >> 6;
  int wid = (blockIdx.x * blockDim.x + threadIdx.x) >> 6;
  int nw = (gridDim.x * blockDim.x) >> 6;
  const h8* w2p = (const h8*)(wbuf + OFF_W2);
  const h8* w3p = (const h8*)(wbuf + OFF_W3);
  h8 w2[16], w3[8];
#pragma unroll
  for (int f = 0; f < 16; ++f) w2[f] = w2p[f * 64 + l];
#pragma unroll
  for (int f = 0; f < 8; ++f) w3[f] = w3p[f * 64 + l];
  float bv2[4], bv3[4];
#pragma unroll
  for (int jt = 0; jt < 4; ++jt) { bv2[jt] = b2[jt * 16 + m16]; bv3[jt] = b3[jt * 16 + m16]; }
  float* myl = lds[wv];
  float* zl  = zls[wv];
  int g = l >> 3, c = l & 7;
  for (int t = wid; t < ntiles; t += nw) {
    int rbase = t * 16;
    // phase 1: gather z rows for the wave's 16 nodes (wave-private LDS, no barrier)
    for (int n = 0; n < 16; ++n) {
      int node = rbase + n;
      int lo = roff[node], hi = roff[node + 1];
      float acc[8];
#pragma unroll
      for (int j = 0; j < 8; ++j) acc[j] = 0.0f;
      for (int i = lo + g; i < hi; i += 8) {
        int r = dstArr[i];
        union { uint2 u; u8 b[8]; } pk;
        pk.u = *(const uint2*)(Xe + (size_t)r * 64 + c * 8);
#pragma unroll
        for (int j = 0; j < 8; ++j) acc[j] += dec8(pk.b[j]);
      }
#pragma unroll
      for (int j = 0; j < 8; ++j) {
        acc[j] += __shfl_xor(acc[j], 8);
        acc[j] += __shfl_xor(acc[j], 16);
        acc[j] += __shfl_xor(acc[j], 32);
      }
      if (g == 0) {
        float s = (hi > lo) ? 1.0f / (SX * (float)(hi - lo)) : 0.0f;
#pragma unroll
        for (int j = 0; j < 8; ++j) zl[n * 68 + c * 8 + j] = acc[j] * s;
      }
    }
    // phase 2: MFMA chain (z frags from LDS)
    const __half* rp = x + (size_t)(rbase + m16) * 64 + q * 8;
    h8 a0 = *(const h8*)rp, a1 = *(const h8*)(rp + 32);
    h8 az0, az1;
#pragma unroll
    for (int j = 0; j < 8; ++j) az0[j] = (_Float16)zl[m16 * 68 + q * 8 + j];
#pragma unroll
    for (int j = 0; j < 8; ++j) az1[j] = (_Float16)zl[m16 * 68 + 32 + q * 8 + j];
    f4 acc[4];
#pragma unroll
    for (int jt = 0; jt < 4; ++jt) {
      acc[jt] = zero4();
      acc[jt] = MFMA(a0,  w2[jt * 4 + 0], acc[jt]);
      acc[jt] = MFMA(a1,  w2[jt * 4 + 1], acc[jt]);
      acc[jt] = MFMA(az0, w2[jt * 4 + 2], acc[jt]);
      acc[jt] = MFMA(az1, w2[jt * 4 + 3], acc[jt]);
    }
#pragma unroll
    for (int r = 0; r < 4; ++r) {
      int row = rbase + q * 4 + r;
      float msk = (roff[row + 1] > roff[row]) ? 0.5f : 0.0f;
#pragma unroll
      for (int jt = 0; jt < 4; ++jt) {
        float val = acc[jt][r] + bv2[jt];
        float x0v = __half2float(x0[(size_t)row * 64 + jt * 16 + m16]);
        myl[(q * 4 + r) * 68 + jt * 16 + m16] = fmaf(msk, val, 0.5f * x0v);
      }
    }
    h8 t0, t1;
#pragma unroll
    for (int j = 0; j < 8; ++j) t0[j] = (_Float16)myl[m16 * 68 + q * 8 + j];
#pragma unroll
    for (int j = 0; j < 8; ++j) t1[j] = (_Float16)myl[m16 * 68 + 32 + q * 8 + j];
#pragma unroll
    for (int jt = 0; jt < 4; ++jt) {
      acc[jt] = zero4();
      acc[jt] = MFMA(t0, w3[jt * 2 + 0], acc[jt]);
      acc[jt] = MFMA(t1, w3[jt * 2 + 1], acc[jt]);
    }
#pragma unroll
    for (int jt = 0; jt < 4; ++jt)
#pragma unroll
      for (int r = 0; r < 4; ++r)
        x[(size_t)(rbase + q * 4 + r) * 64 + jt * 16 + m16] =
            __float2half(fmaxf(acc[jt][r] + bv3[jt], 0.0f));
  }
}

// ---- classifier (unchanged) ----
__global__ void __launch_bounds__(256) classifier_mfma(const __half* __restrict__ x,
    const _Float16* __restrict__ wbuf, const float* __restrict__ bc1,
    const float* __restrict__ bc2, __half* __restrict__ out, int ntiles) {
  __shared__ float lds[4][16 * 68];
  int l = threadIdx.x & 63, q = l >> 4, m16 = l & 15, wv = threadIdx.x >> 6;
  int wid = (blockIdx.x * blockDim.x + threadIdx.x) >> 6;
  int nw = (gridDim.x * blockDim.x) >> 6;
  const h8* w1p = (const h8*)(wbuf + OFF_C1);
  const h8* w2p = (const h8*)(wbuf + OFF_C2);
  h8 w1[8], w2[4];
#pragma unroll
  for (int f = 0; f < 8; ++f) w1[f] = w1p[f * 64 + l];
#pragma unroll
  for (int f = 0; f < 4; ++f) w2[f] = w2p[f * 64 + l];
  float bv1[4], bv2[2];
#pragma unroll
  for (int jt = 0; jt < 4; ++jt) bv1[jt] = bc1[jt * 16 + m16];
#pragma unroll
  for (int jt = 0; jt < 2; ++jt) bv2[jt] = bc2[jt * 16 + m16];
  float* myl = lds[wv];
  for (int t = wid; t < ntiles; t += nw) {
    int rbase = t * 16;
    const __half* rp = x + (size_t)(rbase + m16) * 64 + q * 8;
    h8 a0 = *(const h8*)rp, a1 = *(const h8*)(rp + 32);
    f4 acc[4];
#pragma unroll
    for (int jt = 0; jt < 4; ++jt) {
      acc[jt] = zero4();
      acc[jt] = MFMA(a0, w1[jt * 2 + 0], acc[jt]);
      acc[jt] = MFMA(a1, w1[jt * 2 + 1], acc[jt]);
    }
#pragma unroll
    for (int jt = 0; jt < 4; ++jt)
#pragma unroll
      for (int r = 0; r < 4; ++r)
        myl[(q * 4 + r) * 68 + jt * 16 + m16] = fmaxf(acc[jt][r] + bv1[jt], 0.0f);
    h8 t0, t1;
#pragma unroll
    for (int j = 0; j < 8; ++j) t0[j] = (_Float16)myl[m16 * 68 + q * 8 + j];
#pragma unroll
    for (int j = 0; j < 8; ++j) t1[j] = (_Float16)myl[m16 * 68 + 32 + q * 8 + j];
    f4 o[2];
#pragma unroll
    for (int jt = 0; jt < 2; ++jt) {
      o[jt] = zero4();
      o[jt] = MFMA(t0, w2[jt * 2 + 0], o[jt]);
      o[jt] = MFMA(t1, w2[jt * 2 + 1], o[jt]);
    }
#pragma unroll
    for (int jt = 0; jt < 2; ++jt)
#pragma unroll
      for (int r = 0; r < 4; ++r)
        out[(size_t)(rbase + q * 4 + r) * 32 + jt * 16 + m16] =
            __float2half(o[jt][r] + bv2[jt]);
  }
}

// ---- per-graph mean readout (unchanged) ----
__global__ void __launch_bounds__(256) readout_k(const __half* __restrict__ xc,
    const int* __restrict__ batch, int n, float* __restrict__ out) {
  __shared__ float part[8][32];
  int g = blockIdx.x;
  int lo = lbound(batch, n, g);
  int hi = lbound(batch, n, g + 1);
  int j = threadIdx.x & 31, r = threadIdx.x >> 5;
  float acc = 0.0f;
  for (int i = lo + r; i < hi; i += 8) acc += __half2float(xc[(size_t)i * 32 + j]);
  part[r][j] = acc;
  __syncthreads();
  if (threadIdx.x < 32) {
    float s = 0.0f;
#pragma unroll
    for (int rr = 0; rr < 8; ++rr) s += part[rr][j];
    out[g * 32 + j] = (hi > lo) ? s / (float)(hi - lo) : 0.0f;
  }
}

extern "C" void kernel_launch(void* const* d_in, const int* in_sizes, int n_in,
                              void* d_out, int out_size, void* d_ws, size_t ws_size,
                              hipStream_t stream) {
  const float* X    = (const float*)d_in[0];
  const int*   src  = (const int*)d_in[1];
  const int*   dst  = (const int*)d_in[2];
  const int*   batch= (const int*)d_in[3];
  const float* W_in = (const float*)d_in[4];
  const float* b_in = (const float*)d_in[5];
  const float* W1a  = (const float*)d_in[6];
  const float* b1a  = (const float*)d_in[7];
  const float* W1b  = (const float*)d_in[8];
  const float* b1b  = (const float*)d_in[9];
  const float* W2   = (const float*)d_in[10];
  const float* b2   = (const float*)d_in[11];
  const float* W3   = (const float*)d_in[12];
  const float* b3   = (const float*)d_in[13];
  const float* Wc1  = (const float*)d_in[14];
  const float* bc1  = (const float*)d_in[15];
  const float* Wc2  = (const float*)d_in[16];
  const float* bc2  = (const float*)d_in[17];
  float* out = (float*)d_out;

  // workspace layout (~45 MB)
  float* p  = (float*)d_ws;
  __half* x  = (__half*)p; p += (size_t)NN * 32;  // 12.8 MB fp16
  __half* x0 = (__half*)p; p += (size_t)NN * 32;  // 12.8 MB fp16 (aliased as outc later)
  u8* h = (u8*)p; p += (size_t)NN * 16;           // 6.4 MB fp8
  u8* Xe = (u8*)p; p += (size_t)NE * 16;          // 3.2 MB fp8
  float* invE = p; p += NE;
  _Float16* wbuf = (_Float16*)p; p += WBUF_HALVES / 2 + 16;
  int* q     = (int*)p;
  int* off   = q; q += NE + 1;
  int* bcnt  = q; q += 256;
  int* roff  = q; q += NN + 1;
  int* csr   = q; q += NZ;        // 5.12 MB
  unsigned int* words = (unsigned int*)q; q += CB * CAP;  // 6.4 MB
  __half* outc = x0;        // alias: x0 dead after last catmm_w3

  // CSR-by-dst build + row offsets + weight prep (merged)
  prep_misc_k<<<NBLK_ROW + 68, 256, 0, stream>>>(src, roff, bcnt, NN, NZ,
      W_in, W1a, W1b, W2, W3, Wc1, Wc2, wbuf);
  binA_k<<<NBLK_A, 256, 0, stream>>>(src, dst, bcnt, words);
  binB_k<<<CB, 256, 0, stream>>>(words, bcnt, off, invE, csr, NE, NZ);

  mm_in_mfma<<<1563, 256, 0, stream>>>(X, wbuf, b_in, x, x0, NTILE);

  for (int l = 0; l < 2; ++l) {
    mm_dual_mfma<<<1563, 256, 0, stream>>>(x, wbuf, b1a, b1b, h, NTILE);
    ve_pull_k<<<(NE + 3) / 4, 256, 0, stream>>>(h, csr, off, invE, Xe, NE);
    catmm_w3_mfma<<<1563, 256, 0, stream>>>(x, Xe, x0, roff, dst, wbuf, b2, b3, NTILE);
  }

  classifier_mfma<<<1563, 256, 0, stream>>>(x, wbuf, bc1, bc2, outc, NTILE);
  readout_k<<<NG, 256, 0, stream>>>(outc, batch, NN, out);
}

// Round 13
// 388.693 us; speedup vs baseline: 1.3177x; 1.3177x over previous
//
#include <hip/hip_runtime.h>
#include <hip/hip_fp16.h>

// EquivSetGNN forward, MI355X.
// R13: REVERT R12's zgather-into-catmm fusion (119us/dispatch, 1.15M LDS bank
// conflicts, 16x less gather TLP). Back to R10's separate-kernel structure
// (best: 393us), keeping two safe deltas: (1) prep_misc merge (rowoff + weight
// prep, one dispatch); (2) x0 copy eliminated via ping-pong — layer1 x==x0==A,
// catmm writes B; layer2 x=B, x0=A (in-place B write is wave-tile-local).

constexpr int NN = 100000;   // nodes
constexpr int NE = 50000;    // hyperedges
constexpr int NZ = 1280000;  // incidences
constexpr int NG = 256;      // graphs
constexpr int NTILE = NN / 16;  // 6250 row-tiles of 16
constexpr int CB = 196;         // coarse buckets
constexpr int CAP = 8192;       // bucket region capacity (words)
constexpr int CHUNK = 4000;
constexpr int NBLK_A = NZ / CHUNK;          // 320
constexpr int NBLK_ROW = (NZ + 255) / 256;  // 5000

typedef _Float16 h8 __attribute__((ext_vector_type(8)));
typedef float f4 __attribute__((ext_vector_type(4)));

constexpr int OFF_IN  = 0;
constexpr int OFF_1A  = 8192;
constexpr int OFF_1B  = 12288;
constexpr int OFF_W2  = 16384;
constexpr int OFF_W3  = 24576;
constexpr int OFF_C1  = 28672;
constexpr int OFF_C2  = 32768;
constexpr int WBUF_HALVES = 34816;

__device__ __forceinline__ int lbound(const int* a, int n, int v) {
  int lo = 0, hi = n;
  while (lo < hi) { int m = (lo + hi) >> 1; if (a[m] < v) lo = m + 1; else hi = m; }
  return lo;
}

__device__ __forceinline__ f4 zero4() { f4 z; z[0]=0.f; z[1]=0.f; z[2]=0.f; z[3]=0.f; return z; }

__device__ __forceinline__ h8 ld_a32(const float* p) {
  const f4* v = (const f4*)p;
  f4 lo = v[0], hi = v[1];
  h8 r;
  r[0]=(_Float16)lo[0]; r[1]=(_Float16)lo[1]; r[2]=(_Float16)lo[2]; r[3]=(_Float16)lo[3];
  r[4]=(_Float16)hi[0]; r[5]=(_Float16)hi[1]; r[6]=(_Float16)hi[2]; r[7]=(_Float16)hi[3];
  return r;
}

#define MFMA(a, b, c) __builtin_amdgcn_mfma_f32_16x16x32_f16((a), (b), (c), 0, 0, 0)

// ---- Pass A: coarse bin into fixed-capacity regions, packed ((dst&255)<<24 | src) ----
__global__ void __launch_bounds__(256) binA_k(const int* __restrict__ src,
    const int* __restrict__ dst, int* __restrict__ bcnt, unsigned int* __restrict__ words) {
  __shared__ int cnt[CB];
  __shared__ int base[CB];
  int t = threadIdx.x;
  int start = blockIdx.x * CHUNK;
  for (int i = t; i < CB; i += 256) cnt[i] = 0;
  __syncthreads();
  for (int i = start + t; i < start + CHUNK; i += 256)
    atomicAdd(&cnt[dst[i] >> 8], 1);
  __syncthreads();
  for (int i = t; i < CB; i += 256) base[i] = atomicAdd(&bcnt[i], cnt[i]);
  __syncthreads();
  for (int i = t; i < CB; i += 256) cnt[i] = 0;  // reuse as cursor
  __syncthreads();
  for (int i = start + t; i < start + CHUNK; i += 256) {
    int d = dst[i];
    int b = d >> 8;
    int p = base[b] + atomicAdd(&cnt[b], 1);
    words[(size_t)b * CAP + p] = (unsigned)src[i] | ((unsigned)(d & 255) << 24);
  }
}

// ---- Pass B: per bucket — bucket-base scan, histogram, 256-scan, off/invE,
//      exact scatter via LDS, coalesced copy-out ----
__global__ void __launch_bounds__(256) binB_k(const unsigned int* __restrict__ words,
    const int* __restrict__ bcnt,
    int* __restrict__ off, float* __restrict__ invE, int* __restrict__ csr,
    int ne, int nnz) {
  __shared__ int buf[CAP];
  __shared__ int hist[256];
  __shared__ int sh[256];
  __shared__ int cur[256];
  __shared__ int shb[256];
  int b = blockIdx.x, t = threadIdx.x;
  int e0 = b << 8;
  int ecnt = min(256, ne - e0);
  int cntb = bcnt[b];
  shb[t] = (t < CB) ? bcnt[t] : 0;
  __syncthreads();
  for (int ofs = 1; ofs < 256; ofs <<= 1) {
    int v = (t >= ofs) ? shb[t - ofs] : 0;
    __syncthreads();
    shb[t] += v;
    __syncthreads();
  }
  int gbase = shb[b] - cntb;
  const unsigned int* wp = words + (size_t)b * CAP;
  hist[t] = 0;
  __syncthreads();
  for (int i = t; i < cntb; i += 256) atomicAdd(&hist[wp[i] >> 24], 1);
  __syncthreads();
  int c = hist[t];
  sh[t] = c;
  __syncthreads();
  for (int ofs = 1; ofs < 256; ofs <<= 1) {
    int v = (t >= ofs) ? sh[t - ofs] : 0;
    __syncthreads();
    sh[t] += v;
    __syncthreads();
  }
  int excl = sh[t] - c;
  if (t < ecnt) {
    off[e0 + t] = gbase + excl;
    invE[e0 + t] = 1.0f / (float)max(c, 1);
  }
  if (b == CB - 1 && t == 0) off[ne] = nnz;
  cur[t] = excl;
  __syncthreads();
  for (int i = t; i < cntb; i += 256) {
    unsigned w = wp[i];
    int s = (int)(w & 0xFFFFFFu);
    int p = atomicAdd(&cur[w >> 24], 1);
    if (p < CAP) buf[p] = s;
    else csr[gbase + p] = s;  // statistically never
  }
  __syncthreads();
  int lim = min(cntb, CAP);
  for (int i = t; i < lim; i += 256) csr[gbase + i] = buf[i];
}

// ---- merged: roff from sorted src (+bcnt zero) | weight-fragment prep ----
__global__ void __launch_bounds__(256) prep_misc_k(const int* __restrict__ src,
    int* __restrict__ roff, int* __restrict__ bcnt, int n, int nnz,
    const float* __restrict__ W_in, const float* __restrict__ W1a,
    const float* __restrict__ W1b, const float* __restrict__ W2,
    const float* __restrict__ W3,  const float* __restrict__ Wc1,
    const float* __restrict__ Wc2, _Float16* __restrict__ wbuf) {
  int blk = blockIdx.x;
  if (blk < NBLK_ROW) {
    if (blk == 0 && threadIdx.x < 256) bcnt[threadIdx.x] = 0;
    int i = blk * 256 + threadIdx.x;
    if (i >= nnz) return;
    int s = src[i];
    int prev = (i == 0) ? -1 : src[i - 1];
    for (int v = prev + 1; v <= s; ++v) roff[v] = i;
    if (i == nnz - 1) {
      for (int v = s + 1; v <= n; ++v) roff[v] = nnz;
    }
    return;
  }
  int b = blk - NBLK_ROW;
  int l = threadIdx.x;
  if (l >= 64) return;
  const float* srcw; int K, J; _Float16* dstw; int tile;
  if      (b < 16) { srcw = W_in; K = 128; J = 64; dstw = wbuf + OFF_IN; tile = b; }
  else if (b < 24) { srcw = W1a;  K = 64;  J = 64; dstw = wbuf + OFF_1A; tile = b - 16; }
  else if (b < 32) { srcw = W1b;  K = 64;  J = 64; dstw = wbuf + OFF_1B; tile = b - 24; }
  else if (b < 48) { srcw = W2;   K = 128; J = 64; dstw = wbuf + OFF_W2; tile = b - 32; }
  else if (b < 56) { srcw = W3;   K = 64;  J = 64; dstw = wbuf + OFF_W3; tile = b - 48; }
  else if (b < 64) { srcw = Wc1;  K = 64;  J = 64; dstw = wbuf + OFF_C1; tile = b - 56; }
  else             { srcw = Wc2;  K = 64;  J = 32; dstw = wbuf + OFF_C2; tile = b - 64; }
  int KS = K / 32;
  int jt = tile / KS, ks = tile % KS;
  int q = l >> 4, m = l & 15;
#pragma unroll
  for (int j = 0; j < 8; ++j)
    dstw[((size_t)tile * 64 + l) * 8 + j] =
        (_Float16)srcw[(size_t)(ks * 32 + q * 8 + j) * J + jt * 16 + m];
}

// ---- x = relu(X @ W_in + b). fp16 output (single buffer; serves as x0 too) ----
__global__ void __launch_bounds__(256) mm_in_mfma(const float* __restrict__ A,
    const _Float16* __restrict__ wbuf, const float* __restrict__ b,
    __half* __restrict__ C, int ntiles) {
  int l = threadIdx.x & 63, q = l >> 4, m16 = l & 15;
  int wid = (blockIdx.x * blockDim.x + threadIdx.x) >> 6;
  int nw = (gridDim.x * blockDim.x) >> 6;
  const h8* wf = (const h8*)(wbuf + OFF_IN);
  h8 w[16];
#pragma unroll
  for (int f = 0; f < 16; ++f) w[f] = wf[f * 64 + l];
  float bv[4];
#pragma unroll
  for (int jt = 0; jt < 4; ++jt) bv[jt] = b[jt * 16 + m16];
  for (int t = wid; t < ntiles; t += nw) {
    int rbase = t * 16;
    const float* rp = A + (size_t)(rbase + m16) * 128 + q * 8;
    h8 a0 = ld_a32(rp), a1 = ld_a32(rp + 32), a2 = ld_a32(rp + 64), a3 = ld_a32(rp + 96);
    f4 acc[4];
#pragma unroll
    for (int jt = 0; jt < 4; ++jt) {
      acc[jt] = zero4();
      acc[jt] = MFMA(a0, w[jt * 4 + 0], acc[jt]);
      acc[jt] = MFMA(a1, w[jt * 4 + 1], acc[jt]);
      acc[jt] = MFMA(a2, w[jt * 4 + 2], acc[jt]);
      acc[jt] = MFMA(a3, w[jt * 4 + 3], acc[jt]);
    }
#pragma unroll
    for (int jt = 0; jt < 4; ++jt)
#pragma unroll
      for (int r = 0; r < 4; ++r)
        C[(size_t)(rbase + q * 4 + r) * 64 + jt * 16 + m16] =
            __float2half(fmaxf(acc[jt][r] + bv[jt], 0.0f));
  }
}

// ---- h = relu(x@W1a+b1a)@W1b + b1b; fp16 in/out ----
__global__ void __launch_bounds__(256) mm_dual_mfma(const __half* __restrict__ x,
    const _Float16* __restrict__ wbuf, const float* __restrict__ b1a,
    const float* __restrict__ b1b, __half* __restrict__ h, int ntiles) {
  __shared__ float lds[4][16 * 68];
  int l = threadIdx.x & 63, q = l >> 4, m16 = l & 15, wv = threadIdx.x >> 6;
  int wid = (blockIdx.x * blockDim.x + threadIdx.x) >> 6;
  int nw = (gridDim.x * blockDim.x) >> 6;
  const h8* wap = (const h8*)(wbuf + OFF_1A);
  const h8* wbp = (const h8*)(wbuf + OFF_1B);
  h8 wa[8], wb[8];
#pragma unroll
  for (int f = 0; f < 8; ++f) { wa[f] = wap[f * 64 + l]; wb[f] = wbp[f * 64 + l]; }
  float bav[4], bbv[4];
#pragma unroll
  for (int jt = 0; jt < 4; ++jt) { bav[jt] = b1a[jt * 16 + m16]; bbv[jt] = b1b[jt * 16 + m16]; }
  float* myl = lds[wv];
  for (int t = wid; t < ntiles; t += nw) {
    int rbase = t * 16;
    const __half* rp = x + (size_t)(rbase + m16) * 64 + q * 8;
    h8 a0 = *(const h8*)rp, a1 = *(const h8*)(rp + 32);
    f4 acc[4];
#pragma unroll
    for (int jt = 0; jt < 4; ++jt) {
      acc[jt] = zero4();
      acc[jt] = MFMA(a0, wa[jt * 2 + 0], acc[jt]);
      acc[jt] = MFMA(a1, wa[jt * 2 + 1], acc[jt]);
    }
#pragma unroll
    for (int jt = 0; jt < 4; ++jt)
#pragma unroll
      for (int r = 0; r < 4; ++r)
        myl[(q * 4 + r) * 68 + jt * 16 + m16] = fmaxf(acc[jt][r] + bav[jt], 0.0f);
    h8 t0, t1;
#pragma unroll
    for (int j = 0; j < 8; ++j) t0[j] = (_Float16)myl[m16 * 68 + q * 8 + j];
#pragma unroll
    for (int j = 0; j < 8; ++j) t1[j] = (_Float16)myl[m16 * 68 + 32 + q * 8 + j];
#pragma unroll
    for (int jt = 0; jt < 4; ++jt) {
      acc[jt] = zero4();
      acc[jt] = MFMA(t0, wb[jt * 2 + 0], acc[jt]);
      acc[jt] = MFMA(t1, wb[jt * 2 + 1], acc[jt]);
    }
#pragma unroll
    for (int jt = 0; jt < 4; ++jt)
#pragma unroll
      for (int r = 0; r < 4; ++r)
        h[(size_t)(rbase + q * 4 + r) * 64 + jt * 16 + m16] = __float2half(acc[jt][r] + bbv[jt]);
  }
}

// ---- V->E pull: wave/edge, 8-rows-per-VMEM, shfl tree (R10 structure) ----
__global__ void __launch_bounds__(256) ve_pull_k(const __half* __restrict__ h,
    const int* __restrict__ csr, const int* __restrict__ off,
    const float* __restrict__ invE, __half* __restrict__ Xe, int e) {
  int lane = threadIdx.x & 63;
  int w = (blockIdx.x * blockDim.x + threadIdx.x) >> 6;
  if (w >= e) return;
  int lo = off[w], end = off[w + 1];
  int g = lane >> 3, c = lane & 7;
  float acc[8];
#pragma unroll
  for (int j = 0; j < 8; ++j) acc[j] = 0.0f;
  for (int i = lo + g; i < end; i += 8) {
    int r = csr[i];
    h8 v = *(const h8*)(h + (size_t)r * 64 + c * 8);
#pragma unroll
    for (int j = 0; j < 8; ++j) acc[j] += (float)v[j];
  }
#pragma unroll
  for (int j = 0; j < 8; ++j) {
    acc[j] += __shfl_xor(acc[j], 8);
    acc[j] += __shfl_xor(acc[j], 16);
    acc[j] += __shfl_xor(acc[j], 32);
  }
  if (g == 0) {
    float s = invE[w];
    h8 o;
#pragma unroll
    for (int j = 0; j < 8; ++j) o[j] = (_Float16)(acc[j] * s);
    *(h8*)(Xe + (size_t)w * 64 + c * 8) = o;
  }
}

// ---- E->V pull: wave/node (R10 structure) ----
__global__ void __launch_bounds__(256) zgather_k(const __half* __restrict__ Xe,
    const int* __restrict__ dstArr, const int* __restrict__ roff,
    __half* __restrict__ z, int n) {
  int lane = threadIdx.x & 63;
  int w = (blockIdx.x * blockDim.x + threadIdx.x) >> 6;
  if (w >= n) return;
  int lo = roff[w], hi = roff[w + 1];
  int g = lane >> 3, c = lane & 7;
  float acc[8];
#pragma unroll
  for (int j = 0; j < 8; ++j) acc[j] = 0.0f;
  for (int i = lo + g; i < hi; i += 8) {
    int r = dstArr[i];
    h8 v = *(const h8*)(Xe + (size_t)r * 64 + c * 8);
#pragma unroll
    for (int j = 0; j < 8; ++j) acc[j] += (float)v[j];
  }
#pragma unroll
  for (int j = 0; j < 8; ++j) {
    acc[j] += __shfl_xor(acc[j], 8);
    acc[j] += __shfl_xor(acc[j], 16);
    acc[j] += __shfl_xor(acc[j], 32);
  }
  if (g == 0) {
    float s = (hi > lo) ? 1.0f / (float)(hi - lo) : 0.0f;
    h8 o;
#pragma unroll
    for (int j = 0; j < 8; ++j) o[j] = (_Float16)(acc[j] * s);
    *(h8*)(z + (size_t)w * 64 + c * 8) = o;
  }
}

// ---- fused: res = 0.5*x0 + mask*0.5*(cat(xin,z)@W2+b2); xout = relu(res@W3+b3) ----
// xin may equal xout (wave-tile-local in-place).
__global__ void __launch_bounds__(256) catmm_w3_mfma(const __half* xin,
    const __half* __restrict__ z, const __half* __restrict__ x0,
    const int* __restrict__ roff, const _Float16* __restrict__ wbuf,
    const float* __restrict__ b2, const float* __restrict__ b3,
    __half* xout, int ntiles) {
  __shared__ float lds[4][16 * 68];
  int l = threadIdx.x & 63, q = l >> 4, m16 = l & 15, wv = threadIdx.x >> 6;
  int wid = (blockIdx.x * blockDim.x + threadIdx.x) >> 6;
  int nw = (gridDim.x * blockDim.x) >> 6;
  const h8* w2p = (const h8*)(wbuf + OFF_W2);
  const h8* w3p = (const h8*)(wbuf + OFF_W3);
  h8 w2[16], w3[8];
#pragma unroll
  for (int f = 0; f < 16; ++f) w2[f] = w2p[f * 64 + l];
#pragma unroll
  for (int f = 0; f < 8; ++f) w3[f] = w3p[f * 64 + l];
  float bv2[4], bv3[4];
#pragma unroll
  for (int jt = 0; jt < 4; ++jt) { bv2[jt] = b2[jt * 16 + m16]; bv3[jt] = b3[jt * 16 + m16]; }
  float* myl = lds[wv];
  for (int t = wid; t < ntiles; t += nw) {
    int rbase = t * 16;
    const __half* rp = xin + (size_t)(rbase + m16) * 64 + q * 8;
    h8 a0 = *(const h8*)rp, a1 = *(const h8*)(rp + 32);
    const __half* zr = z + (size_t)(rbase + m16) * 64;
    h8 az0 = *(const h8*)(zr + q * 8), az1 = *(const h8*)(zr + 32 + q * 8);
    f4 acc[4];
#pragma unroll
    for (int jt = 0; jt < 4; ++jt) {
      acc[jt] = zero4();
      acc[jt] = MFMA(a0,  w2[jt * 4 + 0], acc[jt]);
      acc[jt] = MFMA(a1,  w2[jt * 4 + 1], acc[jt]);
      acc[jt] = MFMA(az0, w2[jt * 4 + 2], acc[jt]);
      acc[jt] = MFMA(az1, w2[jt * 4 + 3], acc[jt]);
    }
#pragma unroll
    for (int r = 0; r < 4; ++r) {
      int row = rbase + q * 4 + r;
      float msk = (roff[row + 1] > roff[row]) ? 0.5f : 0.0f;
#pragma unroll
      for (int jt = 0; jt < 4; ++jt) {
        float val = acc[jt][r] + bv2[jt];
        float x0v = __half2float(x0[(size_t)row * 64 + jt * 16 + m16]);
        myl[(q * 4 + r) * 68 + jt * 16 + m16] = fmaf(msk, val, 0.5f * x0v);
      }
    }
    h8 t0, t1;
#pragma unroll
    for (int j = 0; j < 8; ++j) t0[j] = (_Float16)myl[m16 * 68 + q * 8 + j];
#pragma unroll
    for (int j = 0; j < 8; ++j) t1[j] = (_Float16)myl[m16 * 68 + 32 + q * 8 + j];
#pragma unroll
    for (int jt = 0; jt < 4; ++jt) {
      acc[jt] = zero4();
      acc[jt] = MFMA(t0, w3[jt * 2 + 0], acc[jt]);
      acc[jt] = MFMA(t1, w3[jt * 2 + 1], acc[jt]);
    }
#pragma unroll
    for (int jt = 0; jt < 4; ++jt)
#pragma unroll
      for (int r = 0; r < 4; ++r)
        xout[(size_t)(rbase + q * 4 + r) * 64 + jt * 16 + m16] =
            __float2half(fmaxf(acc[jt][r] + bv3[jt], 0.0f));
  }
}

// ---- classifier: fp16 in/out ----
__global__ void __launch_bounds__(256) classifier_mfma(const __half* __restrict__ x,
    const _Float16* __restrict__ wbuf, const float* __restrict__ bc1,
    const float* __restrict__ bc2, __half* __restrict__ out, int ntiles) {
  __shared__ float lds[4][16 * 68];
  int l = threadIdx.x & 63, q = l >> 4, m16 = l & 15, wv = threadIdx.x >> 6;
  int wid = (blockIdx.x * blockDim.x + threadIdx.x) >> 6;
  int nw = (gridDim.x * blockDim.x) >> 6;
  const h8* w1p = (const h8*)(wbuf + OFF_C1);
  const h8* w2p = (const h8*)(wbuf + OFF_C2);
  h8 w1[8], w2[4];
#pragma unroll
  for (int f = 0; f < 8; ++f) w1[f] = w1p[f * 64 + l];
#pragma unroll
  for (int f = 0; f < 4; ++f) w2[f] = w2p[f * 64 + l];
  float bv1[4], bv2[2];
#pragma unroll
  for (int jt = 0; jt < 4; ++jt) bv1[jt] = bc1[jt * 16 + m16];
#pragma unroll
  for (int jt = 0; jt < 2; ++jt) bv2[jt] = bc2[jt * 16 + m16];
  float* myl = lds[wv];
  for (int t = wid; t < ntiles; t += nw) {
    int rbase = t * 16;
    const __half* rp = x + (size_t)(rbase + m16) * 64 + q * 8;
    h8 a0 = *(const h8*)rp, a1 = *(const h8*)(rp + 32);
    f4 acc[4];
#pragma unroll
    for (int jt = 0; jt < 4; ++jt) {
      acc[jt] = zero4();
      acc[jt] = MFMA(a0, w1[jt * 2 + 0], acc[jt]);
      acc[jt] = MFMA(a1, w1[jt * 2 + 1], acc[jt]);
    }
#pragma unroll
    for (int jt = 0; jt < 4; ++jt)
#pragma unroll
      for (int r = 0; r < 4; ++r)
        myl[(q * 4 + r) * 68 + jt * 16 + m16] = fmaxf(acc[jt][r] + bv1[jt], 0.0f);
    h8 t0, t1;
#pragma unroll
    for (int j = 0; j < 8; ++j) t0[j] = (_Float16)myl[m16 * 68 + q * 8 + j];
#pragma unroll
    for (int j = 0; j < 8; ++j) t1[j] = (_Float16)myl[m16 * 68 + 32 + q * 8 + j];
    f4 o[2];
#pragma unroll
    for (int jt = 0; jt < 2; ++jt) {
      o[jt] = zero4();
      o[jt] = MFMA(t0, w2[jt * 2 + 0], o[jt]);
      o[jt] = MFMA(t1, w2[jt * 2 + 1], o[jt]);
    }
#pragma unroll
    for (int jt = 0; jt < 2; ++jt)
#pragma unroll
      for (int r = 0; r < 4; ++r)
        out[(size_t)(rbase + q * 4 + r) * 32 + jt * 16 + m16] =
            __float2half(o[jt][r] + bv2[jt]);
  }
}

// ---- per-graph mean readout; fp16 input ----
__global__ void __launch_bounds__(256) readout_k(const __half* __restrict__ xc,
    const int* __restrict__ batch, int n, float* __restrict__ out) {
  __shared__ float part[8][32];
  int g = blockIdx.x;
  int lo = lbound(batch, n, g);
  int hi = lbound(batch, n, g + 1);
  int j = threadIdx.x & 31, r = threadIdx.x >> 5;
  float acc = 0.0f;
  for (int i = lo + r; i < hi; i += 8) acc += __half2float(xc[(size_t)i * 32 + j]);
  part[r][j] = acc;
  __syncthreads();
  if (threadIdx.x < 32) {
    float s = 0.0f;
#pragma unroll
    for (int rr = 0; rr < 8; ++rr) s += part[rr][j];
    out[g * 32 + j] = (hi > lo) ? s / (float)(hi - lo) : 0.0f;
  }
}

extern "C" void kernel_launch(void* const* d_in, const int* in_sizes, int n_in,
                              void* d_out, int out_size, void* d_ws, size_t ws_size,
                              hipStream_t stream) {
  const float* X    = (const float*)d_in[0];
  const int*   src  = (const int*)d_in[1];
  const int*   dst  = (const int*)d_in[2];
  const int*   batch= (const int*)d_in[3];
  const float* W_in = (const float*)d_in[4];
  const float* b_in = (const float*)d_in[5];
  const float* W1a  = (const float*)d_in[6];
  const float* b1a  = (const float*)d_in[7];
  const float* W1b  = (const float*)d_in[8];
  const float* b1b  = (const float*)d_in[9];
  const float* W2   = (const float*)d_in[10];
  const float* b2   = (const float*)d_in[11];
  const float* W3   = (const float*)d_in[12];
  const float* b3   = (const float*)d_in[13];
  const float* Wc1  = (const float*)d_in[14];
  const float* bc1  = (const float*)d_in[15];
  const float* Wc2  = (const float*)d_in[16];
  const float* bc2  = (const float*)d_in[17];
  float* out = (float*)d_out;

  // workspace layout (~57 MB)
  float* p  = (float*)d_ws;
  __half* xA = (__half*)p; p += (size_t)NN * 32;  // 12.8 MB (x0 after layer 1; outc at end)
  __half* xB = (__half*)p; p += (size_t)NN * 32;  // 12.8 MB (x after layer 1)
  __half* hz = (__half*)p; p += (size_t)NN * 32;  // 12.8 MB: h then z
  __half* Xe = (__half*)p; p += (size_t)NE * 32;  // 6.4 MB
  float* invE = p; p += NE;
  _Float16* wbuf = (_Float16*)p; p += WBUF_HALVES / 2 + 16;
  int* q     = (int*)p;
  int* off   = q; q += NE + 1;
  int* bcnt  = q; q += 256;
  int* roff  = q; q += NN + 1;
  int* csr   = q; q += NZ;        // 5.12 MB
  unsigned int* words = (unsigned int*)q; q += CB * CAP;  // 6.4 MB
  __half* h = hz;
  __half* z = hz;            // alias: h fully consumed by ve_pull before zgather writes z
  __half* outc = xA;         // alias: xA (x0) dead after layer-2 catmm_w3

  // CSR-by-dst build + row offsets + weight prep
  prep_misc_k<<<NBLK_ROW + 68, 256, 0, stream>>>(src, roff, bcnt, NN, NZ,
      W_in, W1a, W1b, W2, W3, Wc1, Wc2, wbuf);
  binA_k<<<NBLK_A, 256, 0, stream>>>(src, dst, bcnt, words);
  binB_k<<<CB, 256, 0, stream>>>(words, bcnt, off, invE, csr, NE, NZ);

  mm_in_mfma<<<1563, 256, 0, stream>>>(X, wbuf, b_in, xA, NTILE);

  // layer 1: x == x0 == xA; output -> xB
  mm_dual_mfma<<<1563, 256, 0, stream>>>(xA, wbuf, b1a, b1b, h, NTILE);
  ve_pull_k<<<(NE + 3) / 4, 256, 0, stream>>>(h, csr, off, invE, Xe, NE);
  zgather_k<<<(NN + 3) / 4, 256, 0, stream>>>(Xe, dst, roff, z, NN);
  catmm_w3_mfma<<<1563, 256, 0, stream>>>(xA, z, xA, roff, wbuf, b2, b3, xB, NTILE);

  // layer 2: x = xB, x0 = xA; output -> xB (in-place, wave-tile-local)
  mm_dual_mfma<<<1563, 256, 0, stream>>>(xB, wbuf, b1a, b1b, h, NTILE);
  ve_pull_k<<<(NE + 3) / 4, 256, 0, stream>>>(h, csr, off, invE, Xe, NE);
  zgather_k<<<(NN + 3) / 4, 256, 0, stream>>>(Xe, dst, roff, z, NN);
  catmm_w3_mfma<<<1563, 256, 0, stream>>>(xB, z, xA, roff, wbuf, b2, b3, xB, NTILE);

  classifier_mfma<<<1563, 256, 0, stream>>>(xB, wbuf, bc1, bc2, outc, NTILE);
  readout_k<<<NG, 256, 0, stream>>>(outc, batch, NN, out);
}